// Round 2
// baseline (5919.463 us; speedup 1.0000x reference)
//
#include <hip/hip_runtime.h>
#include <hip/hip_bf16.h>

#define DEV __device__ __forceinline__

namespace {

constexpr int ROWS = 64 * 4096;        // B*T
constexpr int NE   = ROWS * 64;        // B*T*F = 16,777,216
constexpr int CHUNK = 512;             // T-chunk for gx/gru
constexpr int NCHUNK = 4096 / CHUNK;

// workspace layout (bytes)
constexpr size_t OFF_XC  = 0;                          // bf16 NE          33,554,432
constexpr size_t OFF_MC  = 33554432;                   // u8 NE            16,777,216
constexpr size_t OFF_WC  = 50331648;                   // fp32 132,288     (pad 786,432)
constexpr size_t OFF_ACC = 51118080;                   // 4 KB acc/flags
constexpr size_t OFF_H1  = 51122176;                   // bf16 NE (r1 spans h1+h2)
constexpr size_t OFF_H2  = 84676608;                   // bf16 NE
constexpr size_t OFF_GX  = 118231040;                  // bf16 64*512*384  25,165,824
constexpr size_t OFF_Z   = 143396864;                  // bf16 ROWS*128    67,108,864 (r2 here)
constexpr size_t OFF_HST = 210505728;                  // fp32 64*128
// total ~210.5 MB

// acc region byte offsets
// [0,1040)   : 130 doubles (sum_x 64, sum_x2 64, mask_cnt, loss)
// [1056,1076): 5 int counters (probe)
// [1088,1096): 2 int flags (flagF: 0=bf16 1=fp32; flagM: 0=u8 1=i32 2=bf16 3=f32)
// [1216,1472): 64 float inv2

DEV float rlane(float v, int l) {
    return __int_as_float(__builtin_amdgcn_readlane(__float_as_int(v), l));
}
DEV float bf2f(unsigned short u) { return __uint_as_float(((unsigned int)u) << 16); }
DEV unsigned short f2bf(float f) {
    unsigned int u = __float_as_uint(f);
    unsigned int r = (u + 0x7FFFu + ((u >> 16) & 1u)) >> 16;
    return (unsigned short)r;
}
DEV float gelu_f(float v) { return 0.5f * v * (1.0f + erff(v * 0.70710678118654752f)); }
DEV float sigm_f(float x) { return 1.0f / (1.0f + __expf(-x)); }
DEV float tanh_f(float x) { float t = __expf(2.0f * x); return 1.0f - 2.0f / (t + 1.0f); }

} // namespace

// ---------------- dtype probe (memory-safe: reads within min-size bounds) ----
__global__ __launch_bounds__(256) void k_probe(const unsigned short* __restrict__ xh,
    const unsigned char* __restrict__ mb, int* __restrict__ cnt)
{
    const int g = blockIdx.x * 256 + threadIdx.x;   // 65536 threads
    int hit = 0;
    for (int i = g; i < (1 << 20); i += (1 << 16)) {      // 2 MB of x, safe either dtype
        int tb = (xh[i] >> 8) & 0x7F;
        hit += (tb >= 0x3C && tb <= 0x40) ? 1 : 0;
    }
    int a = 0, b = 0, c = 0, d = 0;
    for (int i = g; i < (1 << 24); i += (1 << 16)) {      // 16 MB of mask (min size)
        unsigned char v = mb[i];
        int r = i & 3;
        a += (v == 1    && r == 0) ? 1 : 0;
        b += (v == 1    && r != 0) ? 1 : 0;
        c += (v == 0x80 && r == 0) ? 1 : 0;
        d += (v == 0x80 && r == 2) ? 1 : 0;
    }
    __shared__ int sm[256];
    int vals[5] = {hit, a, b, c, d};
#pragma unroll
    for (int k = 0; k < 5; ++k) {
        sm[threadIdx.x] = vals[k];
        __syncthreads();
        for (int s = 128; s > 0; s >>= 1) {
            if (threadIdx.x < s) sm[threadIdx.x] += sm[threadIdx.x + s];
            __syncthreads();
        }
        if (threadIdx.x == 0) atomicAdd(cnt + k, sm[0]);
        __syncthreads();
    }
}

__global__ void k_classify(const int* __restrict__ cnt, int* __restrict__ flags)
{
    flags[0] = (cnt[0] > 786432) ? 0 : 1;   // >75% bf16-looking halfwords
    int fm;
    if (cnt[2] > 0) fm = 0;        // value-1 bytes off word boundary -> uint8
    else if (cnt[1] > 0) fm = 1;   // value-1 bytes only at r%4==0 -> int32
    else if (cnt[3] > 0) fm = 2;   // 0x80 at even incl r%4==0 -> bf16 1.0
    else if (cnt[4] > 0) fm = 3;   // 0x80 only at r%4==2 -> f32 1.0
    else fm = 0;
    flags[1] = fm;
}

// ---------------- canonicalize x (bf16) + mask (u8) ----------------
__global__ __launch_bounds__(256) void k_canon_x(const void* __restrict__ x,
    const void* __restrict__ mask, unsigned short* __restrict__ xc,
    unsigned char* __restrict__ mc, const int* __restrict__ flags)
{
    const int fF = flags[0], fM = flags[1];
    for (int i = blockIdx.x * 256 + threadIdx.x; i < NE; i += gridDim.x * 256) {
        unsigned short h;
        if (fF == 0) h = ((const unsigned short*)x)[i];
        else         h = f2bf(((const float*)x)[i]);
        xc[i] = h;
        unsigned char m;
        if (fM == 0)      m = (((const unsigned char*)mask)[i]  != 0) ? 1 : 0;
        else if (fM == 1) m = (((const int*)mask)[i]            != 0) ? 1 : 0;
        else if (fM == 2) m = (((const unsigned short*)mask)[i] != 0) ? 1 : 0;
        else              m = (((const unsigned int*)mask)[i]   != 0) ? 1 : 0;
        mc[i] = m;
    }
}

// ---------------- canonicalize all weights to fp32 ----------------
__global__ __launch_bounds__(256) void k_canon_w(
    const void* p0, const void* p1, const void* p2, const void* p3,
    const void* p4, const void* p5, const void* p6, const void* p7,
    const void* p8, const void* p9, const void* p10, const void* p11,
    const void* p12, const void* p13, float* __restrict__ wc,
    const int* __restrict__ flags)
{
    const int fF = flags[0];
    const void* p; int off, n;
    switch (blockIdx.x) {
        case 0:  p = p0;  off = 0;      n = 4096;  break;  // stem_w
        case 1:  p = p1;  off = 4096;   n = 64;    break;  // stem_b
        case 2:  p = p2;  off = 4160;   n = 12288; break;  // conv_w
        case 3:  p = p3;  off = 16448;  n = 64;    break;  // conv_b
        case 4:  p = p4;  off = 16512;  n = 24576; break;  // w_ih
        case 5:  p = p5;  off = 41088;  n = 49152; break;  // w_hh
        case 6:  p = p6;  off = 90240;  n = 384;   break;  // b_ih
        case 7:  p = p7;  off = 90624;  n = 384;   break;  // b_hh
        case 8:  p = p8;  off = 91008;  n = 16384; break;  // h1_w
        case 9:  p = p9;  off = 107392; n = 128;   break;  // h1_b
        case 10: p = p10; off = 107520; n = 16384; break;  // h2_w
        case 11: p = p11; off = 123904; n = 128;   break;  // h2_b
        case 12: p = p12; off = 124032; n = 8192;  break;  // h3_w
        default: p = p13; off = 132224; n = 64;    break;  // h3_b
    }
    for (int i = threadIdx.x; i < n; i += 256) {
        float v = (fF == 0) ? bf2f(((const unsigned short*)p)[i]) : ((const float*)p)[i];
        wc[off + i] = v;
    }
}

// ---------------- std over features + mask count ----------------
__global__ __launch_bounds__(256) void k_std(const unsigned short* __restrict__ xc,
    const unsigned char* __restrict__ mc, double* __restrict__ acc)
{
    const int tid = threadIdx.x, f = tid & 63, slot = tid >> 6;
    float s = 0.f, sq = 0.f; int cnt = 0;
    for (int row = blockIdx.x * 4 + slot; row < ROWS; row += gridDim.x * 4) {
        const size_t base = (size_t)row * 64 + f;
        float v = bf2f(xc[base]);
        s += v; sq += v * v;
        cnt += mc[base];
    }
    __shared__ float ls[256], lq[256];
    __shared__ int lc[256];
    ls[tid] = s; lq[tid] = sq; lc[tid] = cnt;
    __syncthreads();
    if (tid < 64) {
        float S = ls[tid] + ls[tid + 64] + ls[tid + 128] + ls[tid + 192];
        float Q = lq[tid] + lq[tid + 64] + lq[tid + 128] + lq[tid + 192];
        atomicAdd(acc + tid, (double)S);
        atomicAdd(acc + 64 + tid, (double)Q);
    }
    if (tid == 0) {
        int tot = 0;
        for (int i = 0; i < 256; ++i) tot += lc[i];
        atomicAdd(acc + 128, (double)tot);
    }
}

__global__ void k_scale(const double* __restrict__ acc, float* __restrict__ inv2)
{
    int f = threadIdx.x; // 64 threads
    const double N = (double)ROWS;
    double sum = acc[f], sq = acc[64 + f];
    double var = (sq - sum * sum / N) / (N - 1.0);
    double sd = sqrt(var) + 1e-8;
    inv2[f] = (float)(1.0 / (sd * sd));
}

// ---------------- stem: gelu(xm @ stem_w + b) ----------------
__global__ __launch_bounds__(256) void k_stem(const unsigned short* __restrict__ xc,
    const unsigned char* __restrict__ mc, const float* __restrict__ w,
    const float* __restrict__ b, unsigned short* __restrict__ h1)
{
    const int lane = threadIdx.x & 63;
    const int wid  = blockIdx.x * 4 + (threadIdx.x >> 6);
    const int nw   = gridDim.x * 4;
    float wv[64];
#pragma unroll
    for (int d = 0; d < 64; ++d) wv[d] = w[d * 64 + lane];
    const float bias = b[lane];
    for (int row = wid; row < ROWS; row += nw) {
        const size_t base = (size_t)row * 64;
        float xv = bf2f(xc[base + lane]);
        if (mc[base + lane]) xv = 0.0f;
        float a0 = 0.f, a1 = 0.f, a2 = 0.f, a3 = 0.f;
#pragma unroll
        for (int d = 0; d < 64; d += 4) {
            a0 += rlane(xv, d    ) * wv[d    ];
            a1 += rlane(xv, d + 1) * wv[d + 1];
            a2 += rlane(xv, d + 2) * wv[d + 2];
            a3 += rlane(xv, d + 3) * wv[d + 3];
        }
        h1[base + lane] = f2bf(gelu_f(((a0 + a1) + (a2 + a3)) + bias));
    }
}

// ---------------- conv1d k=3 pad=1 (per batch) + gelu ----------------
__global__ __launch_bounds__(768) void k_conv(const unsigned short* __restrict__ h1,
    const float* __restrict__ cw, const float* __restrict__ cb,
    unsigned short* __restrict__ h2)
{
    __shared__ float parts[3][4][64];
    const int tid = threadIdx.x, lane = tid & 63, wav = tid >> 6; // 12 waves
    const int k = wav >> 2;   // tap 0..2
    const int j = wav & 3;    // row slot 0..3
    float wv[64];
#pragma unroll
    for (int i = 0; i < 64; ++i) wv[i] = cw[lane * 192 + i * 3 + k];
    const float bias = cb[lane];
    const int ntiles = ROWS / 4;
    for (int tile = blockIdx.x; tile < ntiles; tile += gridDim.x) {
        const int row = tile * 4 + j;
        const int t = row & 4095;
        const int src = row + k - 1;
        const bool valid = !((t == 0 && k == 0) || (t == 4095 && k == 2));
        float a0 = 0.f, a1 = 0.f, a2 = 0.f, a3 = 0.f;
        if (valid) {
            float hv = bf2f(h1[(size_t)src * 64 + lane]);
#pragma unroll
            for (int i = 0; i < 64; i += 4) {
                a0 += rlane(hv, i    ) * wv[i    ];
                a1 += rlane(hv, i + 1) * wv[i + 1];
                a2 += rlane(hv, i + 2) * wv[i + 2];
                a3 += rlane(hv, i + 3) * wv[i + 3];
            }
        }
        parts[k][j][lane] = (a0 + a1) + (a2 + a3);
        __syncthreads();
        if (tid < 256) {
            const int jj = tid >> 6;
            const int row2 = tile * 4 + jj;
            float v = parts[0][jj][lane] + parts[1][jj][lane] + parts[2][jj][lane] + bias;
            h2[(size_t)row2 * 64 + lane] = f2bf(gelu_f(v));
        }
        __syncthreads();
    }
}

// ---------------- gx chunk: gelu-free linear, bf16 out ----------------
__global__ __launch_bounds__(192) void k_gx(const unsigned short* __restrict__ h2,
    const float* __restrict__ wih, const float* __restrict__ bih,
    unsigned short* __restrict__ gxc, int t0)
{
    const int tid = threadIdx.x, lane = tid & 63, wav = tid >> 6; // 3 waves
    const int col0 = wav * 128 + lane, col1 = col0 + 64;
    float w0[64], w1[64];
#pragma unroll
    for (int d = 0; d < 64; ++d) {
        w0[d] = wih[(size_t)col0 * 64 + d];
        w1[d] = wih[(size_t)col1 * 64 + d];
    }
    const float b0 = bih[col0], b1 = bih[col1];
    const int nrl = 64 * CHUNK;
    for (int rl = blockIdx.x; rl < nrl; rl += gridDim.x) {
        const int b = rl >> 9, tl = rl & (CHUNK - 1);
        const size_t grow = (size_t)b * 4096 + t0 + tl;
        float hv = bf2f(h2[grow * 64 + lane]);
        float a00 = 0.f, a01 = 0.f, a10 = 0.f, a11 = 0.f;
#pragma unroll
        for (int d = 0; d < 64; d += 2) {
            float m0 = rlane(hv, d), m1 = rlane(hv, d + 1);
            a00 += m0 * w0[d]; a01 += m1 * w0[d + 1];
            a10 += m0 * w1[d]; a11 += m1 * w1[d + 1];
        }
        gxc[(size_t)rl * 384 + col0] = f2bf(a00 + a01 + b0);
        gxc[(size_t)rl * 384 + col1] = f2bf(a10 + a11 + b1);
    }
}

// ---------------- GRU chunk: one block per batch element ----------------
__global__ __launch_bounds__(768) void k_gru(const unsigned short* __restrict__ gxc,
    const float* __restrict__ whh, const float* __restrict__ bhh,
    unsigned short* __restrict__ z, float* __restrict__ hstate, int t0)
{
    __shared__ float hs[128];
    __shared__ float ghp[384 * 5];  // stride 5 breaks bank alias
    const int tid = threadIdx.x, lane = tid & 63, wav = tid >> 6;
    const int q = wav & 3, rb = wav >> 2;          // q: 0..3, rb: 0..2
    const int rowA = rb * 128 + lane, rowB = rowA + 64;
    float wa[32], wb[32];
#pragma unroll
    for (int c = 0; c < 32; ++c) {
        wa[c] = whh[(size_t)rowA * 128 + q * 32 + c];
        wb[c] = whh[(size_t)rowB * 128 + q * 32 + c];
    }
    const int b = blockIdx.x;
    const unsigned short* gxb = gxc + (size_t)b * CHUNK * 384;
    float hv = 0.f, bhr = 0.f, bhz = 0.f, bhn = 0.f;
    float gxr = 0.f, gxz = 0.f, gxn = 0.f;
    if (tid < 128) {
        bhr = bhh[tid]; bhz = bhh[128 + tid]; bhn = bhh[256 + tid];
        hv = (t0 == 0) ? 0.0f : hstate[b * 128 + tid];
        hs[tid] = hv;
        gxr = bf2f(gxb[tid]);
        gxz = bf2f(gxb[128 + tid]);
        gxn = bf2f(gxb[256 + tid]);
    }
    __syncthreads();

    for (int t = 0; t < CHUNK; ++t) {
        float hreg = hs[q * 32 + (lane & 31)];
        float a0 = 0.f, a1 = 0.f, c0 = 0.f, c1 = 0.f;
#pragma unroll
        for (int c = 0; c < 32; c += 2) {
            float m0 = rlane(hreg, c), m1 = rlane(hreg, c + 1);
            a0 += m0 * wa[c]; a1 += m1 * wa[c + 1];
            c0 += m0 * wb[c]; c1 += m1 * wb[c + 1];
        }
        ghp[rowA * 5 + q] = a0 + a1;
        ghp[rowB * 5 + q] = c0 + c1;
        __syncthreads();
        if (tid < 128) {
            const int d = tid;
            float ghr = ghp[d * 5] + ghp[d * 5 + 1] + ghp[d * 5 + 2] + ghp[d * 5 + 3] + bhr;
            float ghz = ghp[(128 + d) * 5] + ghp[(128 + d) * 5 + 1] + ghp[(128 + d) * 5 + 2] + ghp[(128 + d) * 5 + 3] + bhz;
            float ghn = ghp[(256 + d) * 5] + ghp[(256 + d) * 5 + 1] + ghp[(256 + d) * 5 + 2] + ghp[(256 + d) * 5 + 3] + bhn;
            float r  = sigm_f(gxr + ghr);
            float zg = sigm_f(gxz + ghz);
            float n  = tanh_f(gxn + r * ghn);
            hv = (1.0f - zg) * n + zg * hv;
            hs[d] = hv;
            z[((size_t)b * 4096 + t0 + t) * 128 + d] = f2bf(hv);
            const int tn = (t + 1 < CHUNK) ? (t + 1) : (CHUNK - 1);
            const unsigned short* gp = gxb + (size_t)tn * 384;
            gxr = bf2f(gp[d]);
            gxz = bf2f(gp[128 + d]);
            gxn = bf2f(gp[256 + d]);
        }
        __syncthreads();
    }
    if (tid < 128) hstate[b * 128 + tid] = hv;
}

// ---------------- head layer (128 -> 128, gelu) ----------------
__global__ __launch_bounds__(256) void k_head(const unsigned short* __restrict__ in,
    const float* __restrict__ w, const float* __restrict__ bias,
    unsigned short* __restrict__ out)
{
    const int tid = threadIdx.x, lane = tid & 63, wav = tid >> 6;
    const int cg = wav & 1, rs = wav >> 1;
    const int col = cg * 64 + lane;
    float wv[128];
#pragma unroll
    for (int d = 0; d < 128; ++d) wv[d] = w[d * 128 + col];
    const float bb = bias[col];
    for (int row = blockIdx.x * 2 + rs; row < ROWS; row += gridDim.x * 2) {
        const unsigned short* ir = in + (size_t)row * 128;
        float z0 = bf2f(ir[lane]), z1 = bf2f(ir[64 + lane]);
        float a0 = 0.f, a1 = 0.f, a2 = 0.f, a3 = 0.f;
#pragma unroll
        for (int d = 0; d < 64; d += 2) {
            a0 += rlane(z0, d    ) * wv[d    ];
            a1 += rlane(z0, d + 1) * wv[d + 1];
            a2 += rlane(z1, d    ) * wv[64 + d    ];
            a3 += rlane(z1, d + 1) * wv[64 + d + 1];
        }
        out[(size_t)row * 128 + col] = f2bf(gelu_f(((a0 + a1) + (a2 + a3)) + bb));
    }
}

// ---------------- head3 (128 -> 64) + masked normalized MSE ----------------
__global__ __launch_bounds__(256) void k_head3(const unsigned short* __restrict__ r2,
    const float* __restrict__ w, const float* __restrict__ bias,
    const unsigned short* __restrict__ xc, const unsigned char* __restrict__ mc,
    const float* __restrict__ inv2, double* __restrict__ lossacc)
{
    const int tid = threadIdx.x, lane = tid & 63, rs = tid >> 6;
    float wv[128];
#pragma unroll
    for (int d = 0; d < 128; ++d) wv[d] = w[d * 64 + lane];
    const float bb = bias[lane];
    const float iv = inv2[lane];
    float accf = 0.0f;
    double acc = 0.0;
    int spill = 0;
    for (int row = blockIdx.x * 4 + rs; row < ROWS; row += gridDim.x * 4) {
        const unsigned short* ir = r2 + (size_t)row * 128;
        float z0 = bf2f(ir[lane]), z1 = bf2f(ir[64 + lane]);
        float a0 = 0.f, a1 = 0.f, a2 = 0.f, a3 = 0.f;
#pragma unroll
        for (int d = 0; d < 64; d += 2) {
            a0 += rlane(z0, d    ) * wv[d    ];
            a1 += rlane(z0, d + 1) * wv[d + 1];
            a2 += rlane(z1, d    ) * wv[64 + d    ];
            a3 += rlane(z1, d + 1) * wv[64 + d + 1];
        }
        float xr = ((a0 + a1) + (a2 + a3)) + bb;
        const size_t base = (size_t)row * 64 + lane;
        float xv = bf2f(xc[base]);
        float dd = xr - xv;
        accf += mc[base] ? dd * dd * iv : 0.0f;
        if (++spill == 64) { acc += (double)accf; accf = 0.0f; spill = 0; }
    }
    acc += (double)accf;
    __shared__ double red[256];
    red[tid] = acc;
    __syncthreads();
    for (int s = 128; s > 0; s >>= 1) {
        if (tid < s) red[tid] += red[tid + s];
        __syncthreads();
    }
    if (tid == 0) atomicAdd(lossacc, red[0]);
}

__global__ void k_loss(const double* __restrict__ acc, const int* __restrict__ flags,
                       void* __restrict__ out)
{
    double cnt = acc[128];
    double denom = (cnt < 1.0) ? 1.0 : cnt;
    float v = (float)(acc[129] / denom);
    if (flags[0] == 1) ((float*)out)[0] = v;
    else ((unsigned short*)out)[0] = f2bf(v);
}

extern "C" void kernel_launch(void* const* d_in, const int* in_sizes, int n_in,
                              void* d_out, int out_size, void* d_ws, size_t ws_size,
                              hipStream_t stream)
{
    (void)in_sizes; (void)n_in; (void)out_size; (void)ws_size;
    const void* x      = d_in[0];
    const void* mask   = d_in[1];

    char* ws = (char*)d_ws;
    unsigned short* xc  = (unsigned short*)(ws + OFF_XC);
    unsigned char*  mc  = (unsigned char*)(ws + OFF_MC);
    float*          wc  = (float*)(ws + OFF_WC);
    double*         acc = (double*)(ws + OFF_ACC);
    int*            cnt = (int*)(ws + OFF_ACC + 1056);
    int*            flg = (int*)(ws + OFF_ACC + 1088);
    float*          inv2= (float*)(ws + OFF_ACC + 1216);
    unsigned short* h1  = (unsigned short*)(ws + OFF_H1);
    unsigned short* h2  = (unsigned short*)(ws + OFF_H2);
    unsigned short* gxc = (unsigned short*)(ws + OFF_GX);
    unsigned short* z   = (unsigned short*)(ws + OFF_Z);
    unsigned short* r1  = (unsigned short*)(ws + OFF_H1);   // reuses h1+h2
    unsigned short* r2  = (unsigned short*)(ws + OFF_Z);    // reuses z
    float*          hst = (float*)(ws + OFF_HST);

    const float* stem_w = wc + 0;
    const float* stem_b = wc + 4096;
    const float* conv_w = wc + 4160;
    const float* conv_b = wc + 16448;
    const float* w_ih   = wc + 16512;
    const float* w_hh   = wc + 41088;
    const float* b_ih   = wc + 90240;
    const float* b_hh   = wc + 90624;
    const float* h1_w   = wc + 91008;
    const float* h1_b   = wc + 107392;
    const float* h2_w   = wc + 107520;
    const float* h2_b   = wc + 123904;
    const float* h3_w   = wc + 124032;
    const float* h3_b   = wc + 132224;

    hipMemsetAsync(ws + OFF_ACC, 0, 4096, stream);
    k_probe   <<<256, 256, 0, stream>>>((const unsigned short*)x, (const unsigned char*)mask, cnt);
    k_classify<<<1, 1, 0, stream>>>(cnt, flg);
    k_canon_x <<<8192, 256, 0, stream>>>(x, mask, xc, mc, flg);
    k_canon_w <<<14, 256, 0, stream>>>(d_in[2], d_in[3], d_in[4], d_in[5], d_in[6],
                                       d_in[7], d_in[8], d_in[9], d_in[10], d_in[11],
                                       d_in[12], d_in[13], d_in[14], d_in[15], wc, flg);
    k_std  <<<512, 256, 0, stream>>>(xc, mc, acc);
    k_scale<<<1, 64, 0, stream>>>(acc, inv2);
    k_stem <<<1024, 256, 0, stream>>>(xc, mc, stem_w, stem_b, h1);
    k_conv <<<512, 768, 0, stream>>>(h1, conv_w, conv_b, h2);
    for (int c = 0; c < NCHUNK; ++c) {
        k_gx <<<512, 192, 0, stream>>>(h2, w_ih, b_ih, gxc, c * CHUNK);
        k_gru<<<64, 768, 0, stream>>>(gxc, w_hh, b_hh, z, hst, c * CHUNK);
    }
    k_head <<<1024, 256, 0, stream>>>(z, h1_w, h1_b, r1);
    k_head <<<1024, 256, 0, stream>>>(r1, h2_w, h2_b, r2);
    k_head3<<<1024, 256, 0, stream>>>(r2, h3_w, h3_b, xc, mc, inv2, acc + 129);
    k_loss <<<1, 1, 0, stream>>>(acc, flg, d_out);
}

// Round 3
// 4940.395 us; speedup vs baseline: 1.1982x; 1.1982x over previous
//
#include <hip/hip_runtime.h>
#include <hip/hip_bf16.h>

#define DEV __device__ __forceinline__

namespace {

constexpr int ROWS = 64 * 4096;        // B*T
constexpr int NE   = ROWS * 64;        // B*T*F = 16,777,216
constexpr int CHUNK = 512;             // T-chunk for gx/gru
constexpr int NCHUNK = 4096 / CHUNK;

// workspace layout (bytes)
constexpr size_t OFF_XC  = 0;                          // bf16 NE          33,554,432
constexpr size_t OFF_MC  = 33554432;                   // u8 NE            16,777,216
constexpr size_t OFF_WC  = 50331648;                   // fp32 132,288
constexpr size_t OFF_ACC = 51118080;                   // 4 KB acc/flags
constexpr size_t OFF_H1  = 51122176;                   // bf16 NE (r1 spans h1+h2)
constexpr size_t OFF_H2  = 84676608;                   // bf16 NE
constexpr size_t OFF_GX  = 118231040;                  // f16 64*512*384   25,165,824
constexpr size_t OFF_Z   = 143396864;                  // bf16 ROWS*128    67,108,864 (r2 here)
constexpr size_t OFF_HST = 210505728;                  // fp32 64*128
// total ~210.5 MB

DEV float rlane(float v, int l) {
    return __int_as_float(__builtin_amdgcn_readlane(__float_as_int(v), l));
}
DEV float bf2f(unsigned short u) { return __uint_as_float(((unsigned int)u) << 16); }
DEV unsigned short f2bf(float f) {
    unsigned int u = __float_as_uint(f);
    unsigned int r = (u + 0x7FFFu + ((u >> 16) & 1u)) >> 16;
    return (unsigned short)r;
}
DEV float gelu_f(float v) { return 0.5f * v * (1.0f + erff(v * 0.70710678118654752f)); }
DEV float sigm_f(float x) { return 1.0f / (1.0f + __expf(-x)); }
DEV float tanh_f(float x) { float t = __expf(2.0f * x); return 1.0f - 2.0f / (t + 1.0f); }

typedef _Float16 half2v __attribute__((ext_vector_type(2)));

DEV float dot2(half2v a, half2v b, float c) {
#if __has_builtin(__builtin_amdgcn_fdot2)
    return __builtin_amdgcn_fdot2(a, b, c, false);
#else
    return c + (float)a.x * (float)b.x + (float)a.y * (float)b.y;
#endif
}
DEV unsigned short f2h_bits(float f) {
    return __builtin_bit_cast(unsigned short, (_Float16)f);
}
DEV float h2f_bits(unsigned short u) {
    return (float)__builtin_bit_cast(_Float16, u);
}

} // namespace

// ---------------- dtype probe (memory-safe: reads within min-size bounds) ----
__global__ __launch_bounds__(256) void k_probe(const unsigned short* __restrict__ xh,
    const unsigned char* __restrict__ mb, int* __restrict__ cnt)
{
    const int g = blockIdx.x * 256 + threadIdx.x;   // 65536 threads
    int hit = 0;
    for (int i = g; i < (1 << 20); i += (1 << 16)) {      // 2 MB of x, safe either dtype
        int tb = (xh[i] >> 8) & 0x7F;
        hit += (tb >= 0x3C && tb <= 0x40) ? 1 : 0;
    }
    int a = 0, b = 0, c = 0, d = 0;
    for (int i = g; i < (1 << 24); i += (1 << 16)) {      // 16 MB of mask (min size)
        unsigned char v = mb[i];
        int r = i & 3;
        a += (v == 1    && r == 0) ? 1 : 0;
        b += (v == 1    && r != 0) ? 1 : 0;
        c += (v == 0x80 && r == 0) ? 1 : 0;
        d += (v == 0x80 && r == 2) ? 1 : 0;
    }
    __shared__ int sm[256];
    int vals[5] = {hit, a, b, c, d};
#pragma unroll
    for (int k = 0; k < 5; ++k) {
        sm[threadIdx.x] = vals[k];
        __syncthreads();
        for (int s = 128; s > 0; s >>= 1) {
            if (threadIdx.x < s) sm[threadIdx.x] += sm[threadIdx.x + s];
            __syncthreads();
        }
        if (threadIdx.x == 0) atomicAdd(cnt + k, sm[0]);
        __syncthreads();
    }
}

__global__ void k_classify(const int* __restrict__ cnt, int* __restrict__ flags)
{
    flags[0] = (cnt[0] > 786432) ? 0 : 1;   // >75% bf16-looking halfwords
    int fm;
    if (cnt[2] > 0) fm = 0;        // value-1 bytes off word boundary -> uint8
    else if (cnt[1] > 0) fm = 1;   // value-1 bytes only at r%4==0 -> int32
    else if (cnt[3] > 0) fm = 2;   // 0x80 at even incl r%4==0 -> bf16 1.0
    else if (cnt[4] > 0) fm = 3;   // 0x80 only at r%4==2 -> f32 1.0
    else fm = 0;
    flags[1] = fm;
}

// ---------------- canonicalize x (bf16) + mask (u8) ----------------
__global__ __launch_bounds__(256) void k_canon_x(const void* __restrict__ x,
    const void* __restrict__ mask, unsigned short* __restrict__ xc,
    unsigned char* __restrict__ mc, const int* __restrict__ flags)
{
    const int fF = flags[0], fM = flags[1];
    for (int i = blockIdx.x * 256 + threadIdx.x; i < NE; i += gridDim.x * 256) {
        unsigned short h;
        if (fF == 0) h = ((const unsigned short*)x)[i];
        else         h = f2bf(((const float*)x)[i]);
        xc[i] = h;
        unsigned char m;
        if (fM == 0)      m = (((const unsigned char*)mask)[i]  != 0) ? 1 : 0;
        else if (fM == 1) m = (((const int*)mask)[i]            != 0) ? 1 : 0;
        else if (fM == 2) m = (((const unsigned short*)mask)[i] != 0) ? 1 : 0;
        else              m = (((const unsigned int*)mask)[i]   != 0) ? 1 : 0;
        mc[i] = m;
    }
}

// ---------------- canonicalize all weights to fp32 ----------------
__global__ __launch_bounds__(256) void k_canon_w(
    const void* p0, const void* p1, const void* p2, const void* p3,
    const void* p4, const void* p5, const void* p6, const void* p7,
    const void* p8, const void* p9, const void* p10, const void* p11,
    const void* p12, const void* p13, float* __restrict__ wc,
    const int* __restrict__ flags)
{
    const int fF = flags[0];
    const void* p; int off, n;
    switch (blockIdx.x) {
        case 0:  p = p0;  off = 0;      n = 4096;  break;  // stem_w
        case 1:  p = p1;  off = 4096;   n = 64;    break;  // stem_b
        case 2:  p = p2;  off = 4160;   n = 12288; break;  // conv_w
        case 3:  p = p3;  off = 16448;  n = 64;    break;  // conv_b
        case 4:  p = p4;  off = 16512;  n = 24576; break;  // w_ih
        case 5:  p = p5;  off = 41088;  n = 49152; break;  // w_hh
        case 6:  p = p6;  off = 90240;  n = 384;   break;  // b_ih
        case 7:  p = p7;  off = 90624;  n = 384;   break;  // b_hh
        case 8:  p = p8;  off = 91008;  n = 16384; break;  // h1_w
        case 9:  p = p9;  off = 107392; n = 128;   break;  // h1_b
        case 10: p = p10; off = 107520; n = 16384; break;  // h2_w
        case 11: p = p11; off = 123904; n = 128;   break;  // h2_b
        case 12: p = p12; off = 124032; n = 8192;  break;  // h3_w
        default: p = p13; off = 132224; n = 64;    break;  // h3_b
    }
    for (int i = threadIdx.x; i < n; i += 256) {
        float v = (fF == 0) ? bf2f(((const unsigned short*)p)[i]) : ((const float*)p)[i];
        wc[off + i] = v;
    }
}

// ---------------- std over features + mask count ----------------
__global__ __launch_bounds__(256) void k_std(const unsigned short* __restrict__ xc,
    const unsigned char* __restrict__ mc, double* __restrict__ acc)
{
    const int tid = threadIdx.x, f = tid & 63, slot = tid >> 6;
    float s = 0.f, sq = 0.f; int cnt = 0;
    for (int row = blockIdx.x * 4 + slot; row < ROWS; row += gridDim.x * 4) {
        const size_t base = (size_t)row * 64 + f;
        float v = bf2f(xc[base]);
        s += v; sq += v * v;
        cnt += mc[base];
    }
    __shared__ float ls[256], lq[256];
    __shared__ int lc[256];
    ls[tid] = s; lq[tid] = sq; lc[tid] = cnt;
    __syncthreads();
    if (tid < 64) {
        float S = ls[tid] + ls[tid + 64] + ls[tid + 128] + ls[tid + 192];
        float Q = lq[tid] + lq[tid + 64] + lq[tid + 128] + lq[tid + 192];
        atomicAdd(acc + tid, (double)S);
        atomicAdd(acc + 64 + tid, (double)Q);
    }
    if (tid == 0) {
        int tot = 0;
        for (int i = 0; i < 256; ++i) tot += lc[i];
        atomicAdd(acc + 128, (double)tot);
    }
}

__global__ void k_scale(const double* __restrict__ acc, float* __restrict__ inv2)
{
    int f = threadIdx.x; // 64 threads
    const double N = (double)ROWS;
    double sum = acc[f], sq = acc[64 + f];
    double var = (sq - sum * sum / N) / (N - 1.0);
    double sd = sqrt(var) + 1e-8;
    inv2[f] = (float)(1.0 / (sd * sd));
}

// ---------------- stem: gelu(xm @ stem_w + b) ----------------
__global__ __launch_bounds__(256) void k_stem(const unsigned short* __restrict__ xc,
    const unsigned char* __restrict__ mc, const float* __restrict__ w,
    const float* __restrict__ b, unsigned short* __restrict__ h1)
{
    const int lane = threadIdx.x & 63;
    const int wid  = blockIdx.x * 4 + (threadIdx.x >> 6);
    const int nw   = gridDim.x * 4;
    float wv[64];
#pragma unroll
    for (int d = 0; d < 64; ++d) wv[d] = w[d * 64 + lane];
    const float bias = b[lane];
    for (int row = wid; row < ROWS; row += nw) {
        const size_t base = (size_t)row * 64;
        float xv = bf2f(xc[base + lane]);
        if (mc[base + lane]) xv = 0.0f;
        float a0 = 0.f, a1 = 0.f, a2 = 0.f, a3 = 0.f;
#pragma unroll
        for (int d = 0; d < 64; d += 4) {
            a0 += rlane(xv, d    ) * wv[d    ];
            a1 += rlane(xv, d + 1) * wv[d + 1];
            a2 += rlane(xv, d + 2) * wv[d + 2];
            a3 += rlane(xv, d + 3) * wv[d + 3];
        }
        h1[base + lane] = f2bf(gelu_f(((a0 + a1) + (a2 + a3)) + bias));
    }
}

// ---------------- conv1d k=3 pad=1 (per batch) + gelu ----------------
__global__ __launch_bounds__(768) void k_conv(const unsigned short* __restrict__ h1,
    const float* __restrict__ cw, const float* __restrict__ cb,
    unsigned short* __restrict__ h2)
{
    __shared__ float parts[3][4][64];
    const int tid = threadIdx.x, lane = tid & 63, wav = tid >> 6; // 12 waves
    const int k = wav >> 2;   // tap 0..2
    const int j = wav & 3;    // row slot 0..3
    float wv[64];
#pragma unroll
    for (int i = 0; i < 64; ++i) wv[i] = cw[lane * 192 + i * 3 + k];
    const float bias = cb[lane];
    const int ntiles = ROWS / 4;
    for (int tile = blockIdx.x; tile < ntiles; tile += gridDim.x) {
        const int row = tile * 4 + j;
        const int t = row & 4095;
        const int src = row + k - 1;
        const bool valid = !((t == 0 && k == 0) || (t == 4095 && k == 2));
        float a0 = 0.f, a1 = 0.f, a2 = 0.f, a3 = 0.f;
        if (valid) {
            float hv = bf2f(h1[(size_t)src * 64 + lane]);
#pragma unroll
            for (int i = 0; i < 64; i += 4) {
                a0 += rlane(hv, i    ) * wv[i    ];
                a1 += rlane(hv, i + 1) * wv[i + 1];
                a2 += rlane(hv, i + 2) * wv[i + 2];
                a3 += rlane(hv, i + 3) * wv[i + 3];
            }
        }
        parts[k][j][lane] = (a0 + a1) + (a2 + a3);
        __syncthreads();
        if (tid < 256) {
            const int jj = tid >> 6;
            const int row2 = tile * 4 + jj;
            float v = parts[0][jj][lane] + parts[1][jj][lane] + parts[2][jj][lane] + bias;
            h2[(size_t)row2 * 64 + lane] = f2bf(gelu_f(v));
        }
        __syncthreads();
    }
}

// ---------------- gx chunk: linear, f16 out, biases folded ----------------
// gx[row][col]: col<256 -> + b_ih + b_hh (r,z gates); col>=256 -> + b_ih only.
__global__ __launch_bounds__(192) void k_gx(const unsigned short* __restrict__ h2,
    const float* __restrict__ wih, const float* __restrict__ bih,
    const float* __restrict__ bhh, unsigned short* __restrict__ gxc, int t0)
{
    const int tid = threadIdx.x, lane = tid & 63, wav = tid >> 6; // 3 waves
    const int col0 = wav * 128 + lane, col1 = col0 + 64;
    float w0[64], w1[64];
#pragma unroll
    for (int d = 0; d < 64; ++d) {
        w0[d] = wih[(size_t)col0 * 64 + d];
        w1[d] = wih[(size_t)col1 * 64 + d];
    }
    const float b0 = bih[col0] + (col0 < 256 ? bhh[col0] : 0.0f);
    const float b1 = bih[col1] + (col1 < 256 ? bhh[col1] : 0.0f);
    const int nrl = 64 * CHUNK;
    for (int rl = blockIdx.x; rl < nrl; rl += gridDim.x) {
        const int b = rl >> 9, tl = rl & (CHUNK - 1);
        const size_t grow = (size_t)b * 4096 + t0 + tl;
        float hv = bf2f(h2[grow * 64 + lane]);
        float a00 = 0.f, a01 = 0.f, a10 = 0.f, a11 = 0.f;
#pragma unroll
        for (int d = 0; d < 64; d += 2) {
            float m0 = rlane(hv, d), m1 = rlane(hv, d + 1);
            a00 += m0 * w0[d]; a01 += m1 * w0[d + 1];
            a10 += m0 * w1[d]; a11 += m1 * w1[d + 1];
        }
        gxc[(size_t)rl * 384 + col0] = f2h_bits(a00 + a01 + b0);
        gxc[(size_t)rl * 384 + col1] = f2h_bits(a10 + a11 + b1);
    }
}

// ---------------- GRU chunk v2: 64 blocks x 256 threads (4 waves) ----------
// wave = (half = w&1 -> d range, ks = w>>1 -> K half).  d = half*64 + lane.
// Thread owns gate-rows {d, 128+d, 256+d} over k in [ks*64, ks*64+64).
// h broadcast: one packed-f16 LDS word per lane + uniform readlane.
// Gates computed redundantly by both ks halves (each thread keeps fp32 h[d]).
__global__ __launch_bounds__(256) void k_gru(const unsigned short* __restrict__ gxc,
    const float* __restrict__ whh, const float* __restrict__ bhh,
    unsigned short* __restrict__ z, float* __restrict__ hstate, int t0)
{
    __shared__ float ghp[384][2];          // partial sums per K-half
    __shared__ unsigned int hpk[64];       // h as packed f16 pairs: word l = (h[2l], h[2l+1])
    const int tid = threadIdx.x, lane = tid & 63, wav = tid >> 6;
    const int half = wav & 1, ks = wav >> 1;
    const int d = half * 64 + lane;
    const int b = blockIdx.x;

    // weights as f16 pairs (48 VGPRs): rows d, 128+d, 256+d; k-half ks
    half2v wr[32], wz[32], wn[32];
#pragma unroll
    for (int i = 0; i < 32; ++i) {
        const int k0 = ks * 64 + 2 * i;
        wr[i] = half2v{(_Float16)whh[(size_t)d * 128 + k0],
                       (_Float16)whh[(size_t)d * 128 + k0 + 1]};
        wz[i] = half2v{(_Float16)whh[(size_t)(128 + d) * 128 + k0],
                       (_Float16)whh[(size_t)(128 + d) * 128 + k0 + 1]};
        wn[i] = half2v{(_Float16)whh[(size_t)(256 + d) * 128 + k0],
                       (_Float16)whh[(size_t)(256 + d) * 128 + k0 + 1]};
    }
    const float bhn = bhh[256 + d];
    const int kbase = __builtin_amdgcn_readfirstlane(ks * 32);

    const unsigned short* gxb = gxc + (size_t)b * CHUNK * 384;

    float hown;
    if (t0 == 0) hown = 0.0f; else hown = hstate[b * 128 + d];
    if (tid < 64) {
        float h0 = (t0 == 0) ? 0.0f : hstate[b * 128 + 2 * lane];
        float h1 = (t0 == 0) ? 0.0f : hstate[b * 128 + 2 * lane + 1];
        hpk[lane] = (unsigned int)f2h_bits(h0) | ((unsigned int)f2h_bits(h1) << 16);
    }
    // prefetch gx for t=0 (all waves, redundant across ks)
    float gxr = h2f_bits(gxb[d]);
    float gxz = h2f_bits(gxb[128 + d]);
    float gxn = h2f_bits(gxb[256 + d]);
    __syncthreads();

    for (int t = 0; t < CHUNK; ++t) {
        const unsigned int hw = hpk[lane];       // full h, packed pairs
        float sr = 0.f, sz = 0.f, sn = 0.f;
#pragma unroll
        for (int i = 0; i < 32; ++i) {
            const unsigned int p =
                (unsigned int)__builtin_amdgcn_readlane((int)hw, kbase + i);
            const half2v hp = __builtin_bit_cast(half2v, p);
            sr = dot2(hp, wr[i], sr);
            sz = dot2(hp, wz[i], sz);
            sn = dot2(hp, wn[i], sn);
        }
        ghp[d][ks]       = sr;
        ghp[128 + d][ks] = sz;
        ghp[256 + d][ks] = sn;
        __syncthreads();
        {
            const float gr  = ghp[d][0] + ghp[d][1] + gxr;             // bias pre-folded
            const float gz  = ghp[128 + d][0] + ghp[128 + d][1] + gxz; // bias pre-folded
            const float gnh = ghp[256 + d][0] + ghp[256 + d][1] + bhn;
            const float r  = sigm_f(gr);
            const float zg = sigm_f(gz);
            const float n  = tanh_f(gxn + r * gnh);
            hown = n + zg * (hown - n);
            ((unsigned short*)hpk)[d] = f2h_bits(hown);
            if (ks == 0)
                z[((size_t)b * 4096 + t0 + t) * 128 + d] = f2bf(hown);
            const int tn = (t + 1 < CHUNK) ? (t + 1) : (CHUNK - 1);
            gxr = h2f_bits(gxb[(size_t)tn * 384 + d]);
            gxz = h2f_bits(gxb[(size_t)tn * 384 + 128 + d]);
            gxn = h2f_bits(gxb[(size_t)tn * 384 + 256 + d]);
        }
        __syncthreads();
    }
    if (ks == 0) hstate[b * 128 + d] = hown;
}

// ---------------- head layer (128 -> 128, gelu) ----------------
__global__ __launch_bounds__(256) void k_head(const unsigned short* __restrict__ in,
    const float* __restrict__ w, const float* __restrict__ bias,
    unsigned short* __restrict__ out)
{
    const int tid = threadIdx.x, lane = tid & 63, wav = tid >> 6;
    const int cg = wav & 1, rs = wav >> 1;
    const int col = cg * 64 + lane;
    float wv[128];
#pragma unroll
    for (int d = 0; d < 128; ++d) wv[d] = w[d * 128 + col];
    const float bb = bias[col];
    for (int row = blockIdx.x * 2 + rs; row < ROWS; row += gridDim.x * 2) {
        const unsigned short* ir = in + (size_t)row * 128;
        float z0 = bf2f(ir[lane]), z1 = bf2f(ir[64 + lane]);
        float a0 = 0.f, a1 = 0.f, a2 = 0.f, a3 = 0.f;
#pragma unroll
        for (int d = 0; d < 64; d += 2) {
            a0 += rlane(z0, d    ) * wv[d    ];
            a1 += rlane(z0, d + 1) * wv[d + 1];
            a2 += rlane(z1, d    ) * wv[64 + d    ];
            a3 += rlane(z1, d + 1) * wv[64 + d + 1];
        }
        out[(size_t)row * 128 + col] = f2bf(gelu_f(((a0 + a1) + (a2 + a3)) + bb));
    }
}

// ---------------- head3 (128 -> 64) + masked normalized MSE ----------------
__global__ __launch_bounds__(256) void k_head3(const unsigned short* __restrict__ r2,
    const float* __restrict__ w, const float* __restrict__ bias,
    const unsigned short* __restrict__ xc, const unsigned char* __restrict__ mc,
    const float* __restrict__ inv2, double* __restrict__ lossacc)
{
    const int tid = threadIdx.x, lane = tid & 63, rs = tid >> 6;
    float wv[128];
#pragma unroll
    for (int d = 0; d < 128; ++d) wv[d] = w[d * 64 + lane];
    const float bb = bias[lane];
    const float iv = inv2[lane];
    float accf = 0.0f;
    double acc = 0.0;
    int spill = 0;
    for (int row = blockIdx.x * 4 + rs; row < ROWS; row += gridDim.x * 4) {
        const unsigned short* ir = r2 + (size_t)row * 128;
        float z0 = bf2f(ir[lane]), z1 = bf2f(ir[64 + lane]);
        float a0 = 0.f, a1 = 0.f, a2 = 0.f, a3 = 0.f;
#pragma unroll
        for (int d = 0; d < 64; d += 2) {
            a0 += rlane(z0, d    ) * wv[d    ];
            a1 += rlane(z0, d + 1) * wv[d + 1];
            a2 += rlane(z1, d    ) * wv[64 + d    ];
            a3 += rlane(z1, d + 1) * wv[64 + d + 1];
        }
        float xr = ((a0 + a1) + (a2 + a3)) + bb;
        const size_t base = (size_t)row * 64 + lane;
        float xv = bf2f(xc[base]);
        float dd = xr - xv;
        accf += mc[base] ? dd * dd * iv : 0.0f;
        if (++spill == 64) { acc += (double)accf; accf = 0.0f; spill = 0; }
    }
    acc += (double)accf;
    __shared__ double red[256];
    red[tid] = acc;
    __syncthreads();
    for (int s = 128; s > 0; s >>= 1) {
        if (tid < s) red[tid] += red[tid + s];
        __syncthreads();
    }
    if (tid == 0) atomicAdd(lossacc, red[0]);
}

__global__ void k_loss(const double* __restrict__ acc, const int* __restrict__ flags,
                       void* __restrict__ out)
{
    double cnt = acc[128];
    double denom = (cnt < 1.0) ? 1.0 : cnt;
    float v = (float)(acc[129] / denom);
    if (flags[0] == 1) ((float*)out)[0] = v;
    else ((unsigned short*)out)[0] = f2bf(v);
}

extern "C" void kernel_launch(void* const* d_in, const int* in_sizes, int n_in,
                              void* d_out, int out_size, void* d_ws, size_t ws_size,
                              hipStream_t stream)
{
    (void)in_sizes; (void)n_in; (void)out_size; (void)ws_size;
    const void* x      = d_in[0];
    const void* mask   = d_in[1];

    char* ws = (char*)d_ws;
    unsigned short* xc  = (unsigned short*)(ws + OFF_XC);
    unsigned char*  mc  = (unsigned char*)(ws + OFF_MC);
    float*          wc  = (float*)(ws + OFF_WC);
    double*         acc = (double*)(ws + OFF_ACC);
    int*            cnt = (int*)(ws + OFF_ACC + 1056);
    int*            flg = (int*)(ws + OFF_ACC + 1088);
    float*          inv2= (float*)(ws + OFF_ACC + 1216);
    unsigned short* h1  = (unsigned short*)(ws + OFF_H1);
    unsigned short* h2  = (unsigned short*)(ws + OFF_H2);
    unsigned short* gxc = (unsigned short*)(ws + OFF_GX);
    unsigned short* z   = (unsigned short*)(ws + OFF_Z);
    unsigned short* r1  = (unsigned short*)(ws + OFF_H1);   // reuses h1+h2
    unsigned short* r2  = (unsigned short*)(ws + OFF_Z);    // reuses z
    float*          hst = (float*)(ws + OFF_HST);

    const float* stem_w = wc + 0;
    const float* stem_b = wc + 4096;
    const float* conv_w = wc + 4160;
    const float* conv_b = wc + 16448;
    const float* w_ih   = wc + 16512;
    const float* w_hh   = wc + 41088;
    const float* b_ih   = wc + 90240;
    const float* b_hh   = wc + 90624;
    const float* h1_w   = wc + 91008;
    const float* h1_b   = wc + 107392;
    const float* h2_w   = wc + 107520;
    const float* h2_b   = wc + 123904;
    const float* h3_w   = wc + 124032;
    const float* h3_b   = wc + 132224;

    hipMemsetAsync(ws + OFF_ACC, 0, 4096, stream);
    k_probe   <<<256, 256, 0, stream>>>((const unsigned short*)x, (const unsigned char*)mask, cnt);
    k_classify<<<1, 1, 0, stream>>>(cnt, flg);
    k_canon_x <<<8192, 256, 0, stream>>>(x, mask, xc, mc, flg);
    k_canon_w <<<14, 256, 0, stream>>>(d_in[2], d_in[3], d_in[4], d_in[5], d_in[6],
                                       d_in[7], d_in[8], d_in[9], d_in[10], d_in[11],
                                       d_in[12], d_in[13], d_in[14], d_in[15], wc, flg);
    k_std  <<<512, 256, 0, stream>>>(xc, mc, acc);
    k_scale<<<1, 64, 0, stream>>>(acc, inv2);
    k_stem <<<1024, 256, 0, stream>>>(xc, mc, stem_w, stem_b, h1);
    k_conv <<<512, 768, 0, stream>>>(h1, conv_w, conv_b, h2);
    for (int c = 0; c < NCHUNK; ++c) {
        k_gx <<<512, 192, 0, stream>>>(h2, w_ih, b_ih, b_hh, gxc, c * CHUNK);
        k_gru<<<64, 256, 0, stream>>>(gxc, w_hh, b_hh, z, hst, c * CHUNK);
    }
    k_head <<<1024, 256, 0, stream>>>(z, h1_w, h1_b, r1);
    k_head <<<1024, 256, 0, stream>>>(r1, h2_w, h2_b, r2);
    k_head3<<<1024, 256, 0, stream>>>(r2, h3_w, h3_b, xc, mc, inv2, acc + 129);
    k_loss <<<1, 1, 0, stream>>>(acc, flg, d_out);
}

// Round 4
// 4363.925 us; speedup vs baseline: 1.3565x; 1.1321x over previous
//
#include <hip/hip_runtime.h>
#include <hip/hip_bf16.h>

#define DEV __device__ __forceinline__

namespace {

constexpr int ROWS = 64 * 4096;        // B*T
constexpr int NE   = ROWS * 64;        // B*T*F = 16,777,216
constexpr int CHUNK = 512;             // T-chunk for gx/gru
constexpr int NCHUNK = 4096 / CHUNK;

// workspace layout (bytes)
constexpr size_t OFF_XC  = 0;                          // bf16 NE          33,554,432
constexpr size_t OFF_MC  = 33554432;                   // u8 NE            16,777,216
constexpr size_t OFF_WC  = 50331648;                   // fp32 132,288
constexpr size_t OFF_ACC = 51118080;                   // 4 KB acc/flags
constexpr size_t OFF_H1  = 51122176;                   // bf16 NE; gxc1 overlays after conv; r1 (f16, 67MB) spans h1+h2 after GRU
constexpr size_t OFF_H2  = 84676608;                   // bf16 NE
constexpr size_t OFF_GX  = 118231040;                  // f16 64*512*384   25,165,824 (gxc0)
constexpr size_t OFF_Z   = 143396864;                  // f16 ROWS*128     67,108,864 (r2 here)
constexpr size_t OFF_HST = 210505728;                  // fp32 64*128
// total ~210.5 MB

DEV float rlane(float v, int l) {
    return __int_as_float(__builtin_amdgcn_readlane(__float_as_int(v), l));
}
DEV float bf2f(unsigned short u) { return __uint_as_float(((unsigned int)u) << 16); }
DEV unsigned short f2bf(float f) {
    unsigned int u = __float_as_uint(f);
    unsigned int r = (u + 0x7FFFu + ((u >> 16) & 1u)) >> 16;
    return (unsigned short)r;
}
DEV float gelu_f(float v) { return 0.5f * v * (1.0f + erff(v * 0.70710678118654752f)); }
DEV float sigm_f(float x) { return 1.0f / (1.0f + __expf(-x)); }
DEV float tanh_f(float x) { float t = __expf(2.0f * x); return 1.0f - 2.0f / (t + 1.0f); }

typedef _Float16 half2v __attribute__((ext_vector_type(2)));

DEV float dot2(half2v a, half2v b, float c) {
#if __has_builtin(__builtin_amdgcn_fdot2)
    return __builtin_amdgcn_fdot2(a, b, c, false);
#else
    return c + (float)a.x * (float)b.x + (float)a.y * (float)b.y;
#endif
}
DEV unsigned short f2h_bits(float f) {
    return __builtin_bit_cast(unsigned short, (_Float16)f);
}
DEV float h2f_bits(unsigned short u) {
    return (float)__builtin_bit_cast(_Float16, u);
}
// LDS-only barrier: skips the vmcnt(0) drain __syncthreads() would emit.
// Safe here: only LDS ordering is needed across the barrier; global loads/
// stores are consumed via compiler-inserted vmcnt waits at their use sites.
DEV void bar_lds() {
    asm volatile("s_waitcnt lgkmcnt(0)\n\ts_barrier" ::: "memory");
}

} // namespace

// ---------------- dtype probe (memory-safe: reads within min-size bounds) ----
__global__ __launch_bounds__(256) void k_probe(const unsigned short* __restrict__ xh,
    const unsigned char* __restrict__ mb, int* __restrict__ cnt)
{
    const int g = blockIdx.x * 256 + threadIdx.x;   // 65536 threads
    int hit = 0;
    for (int i = g; i < (1 << 20); i += (1 << 16)) {      // 2 MB of x, safe either dtype
        int tb = (xh[i] >> 8) & 0x7F;
        hit += (tb >= 0x3C && tb <= 0x40) ? 1 : 0;
    }
    int a = 0, b = 0, c = 0, d = 0;
    for (int i = g; i < (1 << 24); i += (1 << 16)) {      // 16 MB of mask (min size)
        unsigned char v = mb[i];
        int r = i & 3;
        a += (v == 1    && r == 0) ? 1 : 0;
        b += (v == 1    && r != 0) ? 1 : 0;
        c += (v == 0x80 && r == 0) ? 1 : 0;
        d += (v == 0x80 && r == 2) ? 1 : 0;
    }
    __shared__ int sm[256];
    int vals[5] = {hit, a, b, c, d};
#pragma unroll
    for (int k = 0; k < 5; ++k) {
        sm[threadIdx.x] = vals[k];
        __syncthreads();
        for (int s = 128; s > 0; s >>= 1) {
            if (threadIdx.x < s) sm[threadIdx.x] += sm[threadIdx.x + s];
            __syncthreads();
        }
        if (threadIdx.x == 0) atomicAdd(cnt + k, sm[0]);
        __syncthreads();
    }
}

__global__ void k_classify(const int* __restrict__ cnt, int* __restrict__ flags)
{
    flags[0] = (cnt[0] > 786432) ? 0 : 1;   // >75% bf16-looking halfwords
    int fm;
    if (cnt[2] > 0) fm = 0;        // value-1 bytes off word boundary -> uint8
    else if (cnt[1] > 0) fm = 1;   // value-1 bytes only at r%4==0 -> int32
    else if (cnt[3] > 0) fm = 2;   // 0x80 at even incl r%4==0 -> bf16 1.0
    else if (cnt[4] > 0) fm = 3;   // 0x80 only at r%4==2 -> f32 1.0
    else fm = 0;
    flags[1] = fm;
}

// ---------------- canonicalize x (bf16) + mask (u8) ----------------
__global__ __launch_bounds__(256) void k_canon_x(const void* __restrict__ x,
    const void* __restrict__ mask, unsigned short* __restrict__ xc,
    unsigned char* __restrict__ mc, const int* __restrict__ flags)
{
    const int fF = flags[0], fM = flags[1];
    for (int i = blockIdx.x * 256 + threadIdx.x; i < NE; i += gridDim.x * 256) {
        unsigned short h;
        if (fF == 0) h = ((const unsigned short*)x)[i];
        else         h = f2bf(((const float*)x)[i]);
        xc[i] = h;
        unsigned char m;
        if (fM == 0)      m = (((const unsigned char*)mask)[i]  != 0) ? 1 : 0;
        else if (fM == 1) m = (((const int*)mask)[i]            != 0) ? 1 : 0;
        else if (fM == 2) m = (((const unsigned short*)mask)[i] != 0) ? 1 : 0;
        else              m = (((const unsigned int*)mask)[i]   != 0) ? 1 : 0;
        mc[i] = m;
    }
}

// ---------------- canonicalize all weights to fp32 ----------------
__global__ __launch_bounds__(256) void k_canon_w(
    const void* p0, const void* p1, const void* p2, const void* p3,
    const void* p4, const void* p5, const void* p6, const void* p7,
    const void* p8, const void* p9, const void* p10, const void* p11,
    const void* p12, const void* p13, float* __restrict__ wc,
    const int* __restrict__ flags)
{
    const int fF = flags[0];
    const void* p; int off, n;
    switch (blockIdx.x) {
        case 0:  p = p0;  off = 0;      n = 4096;  break;  // stem_w
        case 1:  p = p1;  off = 4096;   n = 64;    break;  // stem_b
        case 2:  p = p2;  off = 4160;   n = 12288; break;  // conv_w
        case 3:  p = p3;  off = 16448;  n = 64;    break;  // conv_b
        case 4:  p = p4;  off = 16512;  n = 24576; break;  // w_ih
        case 5:  p = p5;  off = 41088;  n = 49152; break;  // w_hh
        case 6:  p = p6;  off = 90240;  n = 384;   break;  // b_ih
        case 7:  p = p7;  off = 90624;  n = 384;   break;  // b_hh
        case 8:  p = p8;  off = 91008;  n = 16384; break;  // h1_w
        case 9:  p = p9;  off = 107392; n = 128;   break;  // h1_b
        case 10: p = p10; off = 107520; n = 16384; break;  // h2_w
        case 11: p = p11; off = 123904; n = 128;   break;  // h2_b
        case 12: p = p12; off = 124032; n = 8192;  break;  // h3_w
        default: p = p13; off = 132224; n = 64;    break;  // h3_b
    }
    for (int i = threadIdx.x; i < n; i += 256) {
        float v = (fF == 0) ? bf2f(((const unsigned short*)p)[i]) : ((const float*)p)[i];
        wc[off + i] = v;
    }
}

// ---------------- std over features + mask count ----------------
__global__ __launch_bounds__(256) void k_std(const unsigned short* __restrict__ xc,
    const unsigned char* __restrict__ mc, double* __restrict__ acc)
{
    const int tid = threadIdx.x, f = tid & 63, slot = tid >> 6;
    float s = 0.f, sq = 0.f; int cnt = 0;
    for (int row = blockIdx.x * 4 + slot; row < ROWS; row += gridDim.x * 4) {
        const size_t base = (size_t)row * 64 + f;
        float v = bf2f(xc[base]);
        s += v; sq += v * v;
        cnt += mc[base];
    }
    __shared__ float ls[256], lq[256];
    __shared__ int lc[256];
    ls[tid] = s; lq[tid] = sq; lc[tid] = cnt;
    __syncthreads();
    if (tid < 64) {
        float S = ls[tid] + ls[tid + 64] + ls[tid + 128] + ls[tid + 192];
        float Q = lq[tid] + lq[tid + 64] + lq[tid + 128] + lq[tid + 192];
        atomicAdd(acc + tid, (double)S);
        atomicAdd(acc + 64 + tid, (double)Q);
    }
    if (tid == 0) {
        int tot = 0;
        for (int i = 0; i < 256; ++i) tot += lc[i];
        atomicAdd(acc + 128, (double)tot);
    }
}

__global__ void k_scale(const double* __restrict__ acc, float* __restrict__ inv2)
{
    int f = threadIdx.x; // 64 threads
    const double N = (double)ROWS;
    double sum = acc[f], sq = acc[64 + f];
    double var = (sq - sum * sum / N) / (N - 1.0);
    double sd = sqrt(var) + 1e-8;
    inv2[f] = (float)(1.0 / (sd * sd));
}

// ---------------- stem: gelu(xm @ stem_w + b) ----------------
__global__ __launch_bounds__(256) void k_stem(const unsigned short* __restrict__ xc,
    const unsigned char* __restrict__ mc, const float* __restrict__ w,
    const float* __restrict__ b, unsigned short* __restrict__ h1)
{
    const int lane = threadIdx.x & 63;
    const int wid  = blockIdx.x * 4 + (threadIdx.x >> 6);
    const int nw   = gridDim.x * 4;
    float wv[64];
#pragma unroll
    for (int d = 0; d < 64; ++d) wv[d] = w[d * 64 + lane];
    const float bias = b[lane];
    for (int row = wid; row < ROWS; row += nw) {
        const size_t base = (size_t)row * 64;
        float xv = bf2f(xc[base + lane]);
        if (mc[base + lane]) xv = 0.0f;
        float a0 = 0.f, a1 = 0.f, a2 = 0.f, a3 = 0.f;
#pragma unroll
        for (int d = 0; d < 64; d += 4) {
            a0 += rlane(xv, d    ) * wv[d    ];
            a1 += rlane(xv, d + 1) * wv[d + 1];
            a2 += rlane(xv, d + 2) * wv[d + 2];
            a3 += rlane(xv, d + 3) * wv[d + 3];
        }
        h1[base + lane] = f2bf(gelu_f(((a0 + a1) + (a2 + a3)) + bias));
    }
}

// ---------------- conv1d k=3 pad=1 (per batch) + gelu ----------------
__global__ __launch_bounds__(768) void k_conv(const unsigned short* __restrict__ h1,
    const float* __restrict__ cw, const float* __restrict__ cb,
    unsigned short* __restrict__ h2)
{
    __shared__ float parts[3][4][64];
    const int tid = threadIdx.x, lane = tid & 63, wav = tid >> 6; // 12 waves
    const int k = wav >> 2;   // tap 0..2
    const int j = wav & 3;    // row slot 0..3
    float wv[64];
#pragma unroll
    for (int i = 0; i < 64; ++i) wv[i] = cw[lane * 192 + i * 3 + k];
    const float bias = cb[lane];
    const int ntiles = ROWS / 4;
    for (int tile = blockIdx.x; tile < ntiles; tile += gridDim.x) {
        const int row = tile * 4 + j;
        const int t = row & 4095;
        const int src = row + k - 1;
        const bool valid = !((t == 0 && k == 0) || (t == 4095 && k == 2));
        float a0 = 0.f, a1 = 0.f, a2 = 0.f, a3 = 0.f;
        if (valid) {
            float hv = bf2f(h1[(size_t)src * 64 + lane]);
#pragma unroll
            for (int i = 0; i < 64; i += 4) {
                a0 += rlane(hv, i    ) * wv[i    ];
                a1 += rlane(hv, i + 1) * wv[i + 1];
                a2 += rlane(hv, i + 2) * wv[i + 2];
                a3 += rlane(hv, i + 3) * wv[i + 3];
            }
        }
        parts[k][j][lane] = (a0 + a1) + (a2 + a3);
        __syncthreads();
        if (tid < 256) {
            const int jj = tid >> 6;
            const int row2 = tile * 4 + jj;
            float v = parts[0][jj][lane] + parts[1][jj][lane] + parts[2][jj][lane] + bias;
            h2[(size_t)row2 * 64 + lane] = f2bf(gelu_f(v));
        }
        __syncthreads();
    }
}

// ---------------- fused: GRU chunk c (blocks < gru_nb) + gx chunk c+1 -------
// GRU role: 512 thr = 8 waves = (K-quarter ks 0..3) x (d-half). Thread owns
// gate-rows {d,128+d,256+d} over 32 k's as f16 pairs. h broadcast: packed-f16
// LDS word/lane + uniform readlane. Partials part[ks][gate][d] (stride-1,
// conflict-free). Raw lgkm-only barriers (no vmcnt drain). gx f16 loads
// double-buffered 8 steps deep in registers.
// gx role: waves 0..5 compute gx = h2 @ w_ih^T (+folded biases) for chunk c+1.
__global__ __launch_bounds__(512) void k_fused(int gru_nb,
    const unsigned short* __restrict__ gx_src, unsigned short* __restrict__ gx_dst,
    const unsigned short* __restrict__ h2,
    const float* __restrict__ wih, const float* __restrict__ bih,
    const float* __restrict__ whh, const float* __restrict__ bhh,
    unsigned short* __restrict__ z, float* __restrict__ hstate,
    int t0_gru, int t0_gx)
{
    const int tid = threadIdx.x, lane = tid & 63, wav = tid >> 6;

    if ((int)blockIdx.x >= gru_nb) {
        // ------------- gx role -------------
        if (wav >= 6) return;
        const int g = blockIdx.x - gru_nb;          // 0..63
        const int colgrp = wav >> 1, rowpar = wav & 1;
        const int col0 = colgrp * 128 + lane, col1 = col0 + 64;
        float w0[64], w1[64];
#pragma unroll
        for (int d = 0; d < 64; ++d) {
            w0[d] = wih[(size_t)col0 * 64 + d];
            w1[d] = wih[(size_t)col1 * 64 + d];
        }
        const float b0 = bih[col0] + (col0 < 256 ? bhh[col0] : 0.0f);
        const float b1 = bih[col1] + (col1 < 256 ? bhh[col1] : 0.0f);
        for (int rl = g * 2 + rowpar; rl < 64 * CHUNK; rl += 128) {
            const int bb = rl >> 9, tl = rl & (CHUNK - 1);
            float hv = bf2f(h2[((size_t)bb * 4096 + t0_gx + tl) * 64 + lane]);
            float a00 = 0.f, a01 = 0.f, a10 = 0.f, a11 = 0.f;
#pragma unroll
            for (int d = 0; d < 64; d += 2) {
                float m0 = rlane(hv, d), m1 = rlane(hv, d + 1);
                a00 += m0 * w0[d]; a01 += m1 * w0[d + 1];
                a10 += m0 * w1[d]; a11 += m1 * w1[d + 1];
            }
            gx_dst[(size_t)rl * 384 + col0] = f2h_bits(a00 + a01 + b0);
            gx_dst[(size_t)rl * 384 + col1] = f2h_bits(a10 + a11 + b1);
        }
        return;
    }

    // ------------- GRU role -------------
    __shared__ float part[4][3][130];
    __shared__ unsigned int hpk[64];   // h as packed f16 pairs
    const int b = blockIdx.x;
    const int half = wav & 1, ksw = wav >> 1;
    const int d = half * 64 + lane;
    const int kb = __builtin_amdgcn_readfirstlane(ksw * 16);

    half2v wr[16], wz[16], wn[16];
#pragma unroll
    for (int i = 0; i < 16; ++i) {
        const int k0 = ksw * 32 + 2 * i;
        wr[i] = half2v{(_Float16)whh[(size_t)d * 128 + k0],
                       (_Float16)whh[(size_t)d * 128 + k0 + 1]};
        wz[i] = half2v{(_Float16)whh[(size_t)(128 + d) * 128 + k0],
                       (_Float16)whh[(size_t)(128 + d) * 128 + k0 + 1]};
        wn[i] = half2v{(_Float16)whh[(size_t)(256 + d) * 128 + k0],
                       (_Float16)whh[(size_t)(256 + d) * 128 + k0 + 1]};
    }
    const float bhn = bhh[256 + d];
    const unsigned short* gxb = gx_src + (size_t)b * CHUNK * 384;

    float hown = 0.0f;
    if (t0_gru > 0 && tid < 128) hown = hstate[b * 128 + tid];
    if (tid < 64) {
        float h0 = 0.f, h1v = 0.f;
        if (t0_gru > 0) {
            h0  = hstate[b * 128 + 2 * lane];
            h1v = hstate[b * 128 + 2 * lane + 1];
        }
        hpk[lane] = (unsigned int)f2h_bits(h0) | ((unsigned int)f2h_bits(h1v) << 16);
    }
    // gx registers: 8 steps current + 8 steps next, 3 gates each (tid<128 only)
    unsigned short cur[24], nxt[24];
    if (tid < 128) {
#pragma unroll
        for (int ti = 0; ti < 8; ++ti)
#pragma unroll
            for (int g3 = 0; g3 < 3; ++g3) {
                cur[ti * 3 + g3] = gxb[(size_t)ti * 384 + g3 * 128 + tid];
                nxt[ti * 3 + g3] = gxb[(size_t)(8 + ti) * 384 + g3 * 128 + tid];
            }
    }
    __syncthreads();

    for (int tb = 0; tb < CHUNK / 8; ++tb) {
#pragma unroll
        for (int ti = 0; ti < 8; ++ti) {
            const unsigned int hw = hpk[lane];
            float sr = 0.f, sz = 0.f, sn = 0.f;
#pragma unroll
            for (int i = 0; i < 16; ++i) {
                const unsigned int p =
                    (unsigned int)__builtin_amdgcn_readlane((int)hw, kb + i);
                const half2v hp = __builtin_bit_cast(half2v, p);
                sr = dot2(hp, wr[i], sr);
                sz = dot2(hp, wz[i], sz);
                sn = dot2(hp, wn[i], sn);
            }
            part[ksw][0][d] = sr;
            part[ksw][1][d] = sz;
            part[ksw][2][d] = sn;
            bar_lds();
            if (tid < 128) {
                const float gr  = part[0][0][tid] + part[1][0][tid] + part[2][0][tid]
                                + part[3][0][tid] + h2f_bits(cur[ti * 3 + 0]);
                const float gz  = part[0][1][tid] + part[1][1][tid] + part[2][1][tid]
                                + part[3][1][tid] + h2f_bits(cur[ti * 3 + 1]);
                const float gnh = part[0][2][tid] + part[1][2][tid] + part[2][2][tid]
                                + part[3][2][tid] + bhn;
                const float r  = sigm_f(gr);
                const float zg = sigm_f(gz);
                const float n  = tanh_f(h2f_bits(cur[ti * 3 + 2]) + r * gnh);
                hown = n + zg * (hown - n);
                ((unsigned short*)hpk)[tid] = f2h_bits(hown);
                z[((size_t)b * 4096 + t0_gru + tb * 8 + ti) * 128 + tid] = f2h_bits(hown);
            }
            bar_lds();
        }
        // 8-step boundary: rotate gx buffers, issue next batch of loads
        if (tid < 128) {
#pragma unroll
            for (int j = 0; j < 24; ++j) cur[j] = nxt[j];
            const int tnb = (tb + 2 <= CHUNK / 8 - 1) ? (tb + 2) * 8 : (CHUNK - 8);
#pragma unroll
            for (int ti = 0; ti < 8; ++ti)
#pragma unroll
                for (int g3 = 0; g3 < 3; ++g3)
                    nxt[ti * 3 + g3] = gxb[(size_t)(tnb + ti) * 384 + g3 * 128 + tid];
        }
    }
    if (tid < 128) hstate[b * 128 + tid] = hown;
}

// ---------------- head layer (128 -> 128, gelu), f16 in/out ----------------
__global__ __launch_bounds__(256) void k_head(const unsigned short* __restrict__ in,
    const float* __restrict__ w, const float* __restrict__ bias,
    unsigned short* __restrict__ out)
{
    const int tid = threadIdx.x, lane = tid & 63, wav = tid >> 6;
    const int cg = wav & 1, rs = wav >> 1;
    const int col = cg * 64 + lane;
    float wv[128];
#pragma unroll
    for (int d = 0; d < 128; ++d) wv[d] = w[d * 128 + col];
    const float bb = bias[col];
    for (int row = blockIdx.x * 2 + rs; row < ROWS; row += gridDim.x * 2) {
        const unsigned short* ir = in + (size_t)row * 128;
        float z0 = h2f_bits(ir[lane]), z1 = h2f_bits(ir[64 + lane]);
        float a0 = 0.f, a1 = 0.f, a2 = 0.f, a3 = 0.f;
#pragma unroll
        for (int d = 0; d < 64; d += 2) {
            a0 += rlane(z0, d    ) * wv[d    ];
            a1 += rlane(z0, d + 1) * wv[d + 1];
            a2 += rlane(z1, d    ) * wv[64 + d    ];
            a3 += rlane(z1, d + 1) * wv[64 + d + 1];
        }
        out[(size_t)row * 128 + col] = f2h_bits(gelu_f(((a0 + a1) + (a2 + a3)) + bb));
    }
}

// ---------------- head3 (128 -> 64) + masked normalized MSE ----------------
__global__ __launch_bounds__(256) void k_head3(const unsigned short* __restrict__ r2,
    const float* __restrict__ w, const float* __restrict__ bias,
    const unsigned short* __restrict__ xc, const unsigned char* __restrict__ mc,
    const float* __restrict__ inv2, double* __restrict__ lossacc)
{
    const int tid = threadIdx.x, lane = tid & 63, rs = tid >> 6;
    float wv[128];
#pragma unroll
    for (int d = 0; d < 128; ++d) wv[d] = w[d * 64 + lane];
    const float bb = bias[lane];
    const float iv = inv2[lane];
    float accf = 0.0f;
    double acc = 0.0;
    int spill = 0;
    for (int row = blockIdx.x * 4 + rs; row < ROWS; row += gridDim.x * 4) {
        const unsigned short* ir = r2 + (size_t)row * 128;
        float z0 = h2f_bits(ir[lane]), z1 = h2f_bits(ir[64 + lane]);
        float a0 = 0.f, a1 = 0.f, a2 = 0.f, a3 = 0.f;
#pragma unroll
        for (int d = 0; d < 64; d += 2) {
            a0 += rlane(z0, d    ) * wv[d    ];
            a1 += rlane(z0, d + 1) * wv[d + 1];
            a2 += rlane(z1, d    ) * wv[64 + d    ];
            a3 += rlane(z1, d + 1) * wv[64 + d + 1];
        }
        float xr = ((a0 + a1) + (a2 + a3)) + bb;
        const size_t base = (size_t)row * 64 + lane;
        float xv = bf2f(xc[base]);
        float dd = xr - xv;
        accf += mc[base] ? dd * dd * iv : 0.0f;
        if (++spill == 64) { acc += (double)accf; accf = 0.0f; spill = 0; }
    }
    acc += (double)accf;
    __shared__ double red[256];
    red[tid] = acc;
    __syncthreads();
    for (int s = 128; s > 0; s >>= 1) {
        if (tid < s) red[tid] += red[tid + s];
        __syncthreads();
    }
    if (tid == 0) atomicAdd(lossacc, red[0]);
}

__global__ void k_loss(const double* __restrict__ acc, const int* __restrict__ flags,
                       void* __restrict__ out)
{
    double cnt = acc[128];
    double denom = (cnt < 1.0) ? 1.0 : cnt;
    float v = (float)(acc[129] / denom);
    if (flags[0] == 1) ((float*)out)[0] = v;
    else ((unsigned short*)out)[0] = f2bf(v);
}

extern "C" void kernel_launch(void* const* d_in, const int* in_sizes, int n_in,
                              void* d_out, int out_size, void* d_ws, size_t ws_size,
                              hipStream_t stream)
{
    (void)in_sizes; (void)n_in; (void)out_size; (void)ws_size;
    const void* x      = d_in[0];
    const void* mask   = d_in[1];

    char* ws = (char*)d_ws;
    unsigned short* xc  = (unsigned short*)(ws + OFF_XC);
    unsigned char*  mc  = (unsigned char*)(ws + OFF_MC);
    float*          wc  = (float*)(ws + OFF_WC);
    double*         acc = (double*)(ws + OFF_ACC);
    int*            cnt = (int*)(ws + OFF_ACC + 1056);
    int*            flg = (int*)(ws + OFF_ACC + 1088);
    float*          inv2= (float*)(ws + OFF_ACC + 1216);
    unsigned short* h1  = (unsigned short*)(ws + OFF_H1);
    unsigned short* h2  = (unsigned short*)(ws + OFF_H2);
    unsigned short* gx0 = (unsigned short*)(ws + OFF_GX);
    unsigned short* gx1 = (unsigned short*)(ws + OFF_H1);   // overlays dead h1
    unsigned short* z   = (unsigned short*)(ws + OFF_Z);
    unsigned short* r1  = (unsigned short*)(ws + OFF_H1);   // after GRU, spans h1+h2
    unsigned short* r2  = (unsigned short*)(ws + OFF_Z);    // reuses z
    float*          hst = (float*)(ws + OFF_HST);

    const float* stem_w = wc + 0;
    const float* stem_b = wc + 4096;
    const float* conv_w = wc + 4160;
    const float* conv_b = wc + 16448;
    const float* w_ih   = wc + 16512;
    const float* w_hh   = wc + 41088;
    const float* b_ih   = wc + 90240;
    const float* b_hh   = wc + 90624;
    const float* h1_w   = wc + 91008;
    const float* h1_b   = wc + 107392;
    const float* h2_w   = wc + 107520;
    const float* h2_b   = wc + 123904;
    const float* h3_w   = wc + 124032;
    const float* h3_b   = wc + 132224;

    unsigned short* bufs[2] = {gx0, gx1};

    hipMemsetAsync(ws + OFF_ACC, 0, 4096, stream);
    k_probe   <<<256, 256, 0, stream>>>((const unsigned short*)x, (const unsigned char*)mask, cnt);
    k_classify<<<1, 1, 0, stream>>>(cnt, flg);
    k_canon_x <<<8192, 256, 0, stream>>>(x, mask, xc, mc, flg);
    k_canon_w <<<14, 256, 0, stream>>>(d_in[2], d_in[3], d_in[4], d_in[5], d_in[6],
                                       d_in[7], d_in[8], d_in[9], d_in[10], d_in[11],
                                       d_in[12], d_in[13], d_in[14], d_in[15], wc, flg);
    k_std  <<<512, 256, 0, stream>>>(xc, mc, acc);
    k_scale<<<1, 64, 0, stream>>>(acc, inv2);
    k_stem <<<1024, 256, 0, stream>>>(xc, mc, stem_w, stem_b, h1);
    k_conv <<<512, 768, 0, stream>>>(h1, conv_w, conv_b, h2);
    // gx for chunk 0 (all 64 blocks in gx role)
    k_fused<<<64, 512, 0, stream>>>(0, bufs[0], bufs[0], h2, w_ih, b_ih,
                                    w_hh, b_hh, z, hst, 0, 0);
    for (int c = 0; c < NCHUNK; ++c) {
        const int ngx = (c + 1 < NCHUNK) ? 64 : 0;
        k_fused<<<64 + ngx, 512, 0, stream>>>(64, bufs[c & 1], bufs[(c + 1) & 1],
                                              h2, w_ih, b_ih, w_hh, b_hh,
                                              z, hst, c * CHUNK, (c + 1) * CHUNK);
    }
    k_head <<<1024, 256, 0, stream>>>(z, h1_w, h1_b, r1);
    k_head <<<1024, 256, 0, stream>>>(r1, h2_w, h2_b, r2);
    k_head3<<<1024, 256, 0, stream>>>(r2, h3_w, h3_b, xc, mc, inv2, acc + 129);
    k_loss <<<1, 1, 0, stream>>>(acc, flg, d_out);
}